// Round 4
// baseline (67885.992 us; speedup 1.0000x reference)
//
#include <hip/hip_runtime.h>
#include <hip/hip_bf16.h>

#define B_   2048
#define L_   128
#define V_   64
#define H_   501
#define T_   127
#define BT_  16
#define NWG_ 128
#define NTH_ 512

typedef __attribute__((ext_vector_type(8))) short short8;
typedef __attribute__((ext_vector_type(4))) float f32x4;

#define MFMA(acc, a, b) acc = __builtin_amdgcn_mfma_f32_16x16x32_bf16((a), (b), (acc), 0, 0, 0)

__device__ __forceinline__ float sigm(float x){ return 1.f/(1.f + __expf(-x)); }
__device__ __forceinline__ float tanh_(float x){ float e = __expf(2.f*x); return 1.f - 2.f/(e + 1.f); }
__device__ __forceinline__ unsigned short f2bf(float x){
  unsigned u = __float_as_uint(x);
  u += 0x7fffu + ((u >> 16) & 1u);
  return (unsigned short)(u >> 16);
}

// ---- prologue kernels (verified) ----

__global__ void k_pack_w(const float* w0,const float* w1,const float* w2,const float* w3,const float* w4,
                         unsigned short* dst){
  int idx = blockIdx.x*256 + threadIdx.x;
  if (idx >= 15*32*16*512) return;
  int e  = idx & 7;
  int l  = (idx>>3) & 63;
  int s  = (idx>>9) & 15;
  int jt = (idx>>13) & 31;
  int mg = idx >> 18;
  int mtx = mg/3, g = mg%3;
  int j = jt*16 + (l & 15);
  int k = s*32 + ((l>>4)&3)*8 + e;
  const float* src = (mtx==0)?w0:(mtx==1)?w1:(mtx==2)?w2:(mtx==3)?w3:w4;
  float v = 0.f;
  if (j < H_ && k < H_) v = src[(size_t)(g*H_ + j)*H_ + k];
  dst[idx] = f2bf(v);
}

__global__ void k_pack_linw(const float* lw, unsigned short* dst){
  int idx = blockIdx.x*256 + threadIdx.x;
  if (idx >= 4*16*512) return;
  int e  = idx & 7;
  int l  = (idx>>3) & 63;
  int s  = (idx>>9) & 15;
  int jt = idx >> 13;
  int j = jt*16 + (l & 15);
  int k = s*32 + ((l>>4)&3)*8 + e;
  dst[idx] = f2bf((k < H_) ? lw[j*H_ + k] : 0.f);
}

__global__ void k_pack_bias(const float* b0,const float* b1,const float* b2,const float* b3,const float* b4,
                            float* dst){
  int idx = blockIdx.x*256 + threadIdx.x;
  if (idx >= 5*1536) return;
  int j = idx & 511; int g = (idx>>9)%3; int l = idx/1536;
  const float* s = (l==0)?b0:(l==1)?b1:(l==2)?b2:(l==3)?b3:b4;
  dst[idx] = (j < H_) ? s[g*H_ + j] : 0.f;
}

__global__ void k_ew(const float* emb, const float* wih0, float* EW){
  int idx = blockIdx.x*256 + threadIdx.x;
  if (idx >= 64*1536) return;
  int j = idx & 511; int g = (idx>>9)%3; int v = idx/1536;
  float s = 0.f;
  if (j < H_){
    const float* wr = wih0 + (size_t)(g*H_ + j)*257;
    const float* e  = emb + v*128;
    for (int k=0;k<128;++k) s += e[k]*wr[k];
  }
  EW[idx] = s;
}

__global__ void k_cb(const float* z, const float* y, const float* bih0, const float* wih0, float* Cb){
  int idx = blockIdx.x*256 + threadIdx.x;
  if (idx >= B_*1536) return;
  int j = idx & 511; int g = (idx>>9)%3; int b = idx/1536;
  float s = 0.f;
  if (j < H_){
    int row = g*H_ + j;
    const float* wr = wih0 + (size_t)row*257 + 128;
    const float* zr = z + b*128;
    s = bih0[row] + y[b]*wr[128];
    for (int k=0;k<128;++k) s += zr[k]*wr[k];
  }
  Cb[idx] = s;
}

__global__ void k_out0(float* out){
  int idx = blockIdx.x*256 + threadIdx.x;
  if (idx >= B_*64) return;
  int v = idx & 63, b = idx >> 6;
  out[(size_t)b*(L_*V_) + v] = (v==1) ? 1.f : 0.f;
}

// zero the pacing-barrier counter (runs first in every launch/graph replay)
__global__ void k_zero(unsigned* bar){
  if (threadIdx.x < 16) bar[threadIdx.x] = 0u;
}

// ---- main persistent GRU kernel ----

#define L0_LOAD(SLOT, ITN) do{                                              \
  const int itn_ = (ITN);                                                   \
  int jt_ = wid + 8*(itn_>>4);                                              \
  size_t o_ = (size_t)jt_*8192 + (size_t)(itn_&15)*512;                     \
  rb0[SLOT][0] = *(const short8*)(wl + o_);                                 \
  rb0[SLOT][1] = *(const short8*)(wl + o_ + 262144);                        \
  rb0[SLOT][2] = *(const short8*)(wl + o_ + 524288); }while(0)

#define L12_LOAD(SLOT, ITN, MIBASE) do{                                     \
  const int itn_ = (ITN);                                                   \
  int jt_ = wid + 8*(itn_>>4);                                              \
  const unsigned short* p_ = wl + (size_t)(MIBASE)*786432                   \
                           + (size_t)jt_*8192 + (size_t)(itn_&15)*512;      \
  rb1[SLOT][0] = *(const short8*)(p_);                                      \
  rb1[SLOT][1] = *(const short8*)(p_ + 262144);                             \
  rb1[SLOT][2] = *(const short8*)(p_ + 524288);                             \
  rb1[SLOT][3] = *(const short8*)(p_ + 786432);                             \
  rb1[SLOT][4] = *(const short8*)(p_ + 1048576);                            \
  rb1[SLOT][5] = *(const short8*)(p_ + 1310720); }while(0)

#define LL_LOAD(SLOT, S) do{                                                \
  rbL[SLOT] = *(const short8*)(ll + (size_t)wid*8192 + (size_t)(S)*512); }while(0)

#define AFRAG(LYR, S) (*(const short8*)((const char*)hsh + (LYR)*16384 +    \
  ((((lcol<<10) + ((S)<<6) + (lrow<<4))) ^ ((lcol&7)<<4))))

#define HWRITE(LYR) do{                                                     \
  _Pragma("unroll")                                                         \
  for (int tt=0; tt<4; ++tt){                                               \
    const int j = (wid + 8*tt)*16 + lcol;                                   \
    _Pragma("unroll")                                                       \
    for (int i=0;i<4;++i){                                                  \
      const int m = lrow*4+i;                                               \
      int byte = (m<<10) + (j<<1); byte ^= ((m&7)<<4);                      \
      *(unsigned short*)((char*)hsh + (LYR)*16384 + byte) = f2bf(hm[LYR][tt][i]); \
    }                                                                       \
  } }while(0)

__global__ __launch_bounds__(NTH_, 2) void k_gru(
  const int* __restrict__ xin, const unsigned short* __restrict__ Wf,
  const unsigned short* __restrict__ LinWf, const float* __restrict__ EW,
  const float* __restrict__ Cb, const float* __restrict__ biasP,
  const float* __restrict__ linb, float* __restrict__ out,
  unsigned* __restrict__ bar)
{
  // 48 KB live + pad -> ~83.5 KB -> forces 1 WG/CU (128 WGs spread over 128 CUs)
  __shared__ unsigned short hsh[3*16*512 + 18176];

  const int tid  = threadIdx.x;
  const int wid  = tid >> 6;
  const int lane = tid & 63;
  const int lrow = lane >> 4;
  const int lcol = lane & 15;
  const int b0   = blockIdx.x * BT_;

  for (int i = tid; i < 3*16*512; i += NTH_) hsh[i] = 0;

  float hm[3][4][4];
  #pragma unroll
  for (int l=0;l<3;++l)
    #pragma unroll
    for (int tt=0;tt<4;++tt)
      #pragma unroll
      for (int i=0;i<4;++i) hm[l][tt][i]=0.f;

  __syncthreads();

  const unsigned short* wl = Wf    + lane*8;
  const unsigned short* ll = LinWf + lane*8;
  const f32x4 z4 = {0.f,0.f,0.f,0.f};

  short8 rb0[4][3];
  short8 rb1[4][6];
  short8 rbL[4];
  int tokn[4];

  // prime layer0 ring for step 0
  #pragma unroll
  for (int p=0;p<4;++p) L0_LOAD(p, p);

  #pragma unroll 1
  for (int t = 0; t < T_; ++t){
    int tok[4];
    #pragma unroll
    for (int i=0;i<4;++i) tok[i] = (t==0) ? 1 : tokn[i];
    #pragma unroll
    for (int i=0;i<4;++i) tokn[i] = xin[(b0+lrow*4+i)*L_ + (t+1)];

    // ================= LAYER 0 =================
    #pragma unroll
    for (int tt=0; tt<4; ++tt){
      const int j = (wid + 8*tt)*16 + lcol;
      f32x4 aR=z4, aZ=z4, aN=z4;
      float gr[4], gz[4], gn[4];
      float br=0.f, bz=0.f, bn=0.f;
      #pragma unroll
      for (int m=0;m<4;++m){
        if (m==2){
          br = biasP[j]; bz = biasP[512+j]; bn = biasP[1024+j];
          #pragma unroll
          for (int i=0;i<4;++i){
            const float* ewp = EW + tok[i]*1536;
            const float* cbp = Cb + (size_t)(b0+lrow*4+i)*1536;
            gr[i] = ewp[j]      + cbp[j];
            gz[i] = ewp[512+j]  + cbp[512+j];
            gn[i] = ewp[1024+j] + cbp[1024+j];
          }
        }
        #pragma unroll
        for (int k=0;k<4;++k){
          const int s = m*4+k;
          short8 a = AFRAG(0, s);
          MFMA(aR, a, rb0[k][0]);
          MFMA(aZ, a, rb0[k][1]);
          MFMA(aN, a, rb0[k][2]);
          if (tt*16 + s + 4 < 64) L0_LOAD(k, tt*16 + s + 4);
        }
      }
      #pragma unroll
      for (int i=0;i<4;++i){
        float hp = hm[0][tt][i];
        float r  = sigm(gr[i] + aR[i] + br);
        float zg = sigm(gz[i] + aZ[i] + bz);
        float n  = tanh_(gn[i] + r*(aN[i] + bn));
        float hnew = (1.f - zg)*n + zg*hp;
        hm[0][tt][i] = (j < H_) ? hnew : 0.f;
      }
    }
    // prime layer1 ring (rb0 dead; latency hides under write-back + barriers)
    #pragma unroll
    for (int p=0;p<4;++p) L12_LOAD(p, p, 1);
    __syncthreads();
    HWRITE(0);
    __syncthreads();

    // ================= LAYER 1 =================
    #pragma unroll
    for (int tt=0; tt<4; ++tt){
      const int j = (wid + 8*tt)*16 + lcol;
      f32x4 aR=z4, aZ=z4, aNI=z4, aNH=z4;
      float bir=0.f,biz=0.f,bin=0.f,bhr=0.f,bhz=0.f,bhn=0.f;
      #pragma unroll
      for (int m=0;m<4;++m){
        if (m==2){
          bir = biasP[1*1536 + j]; biz = biasP[1*1536 + 512 + j]; bin = biasP[1*1536 + 1024 + j];
          bhr = biasP[2*1536 + j]; bhz = biasP[2*1536 + 512 + j]; bhn = biasP[2*1536 + 1024 + j];
        }
        #pragma unroll
        for (int k=0;k<4;++k){
          const int s = m*4+k;
          short8 ap = AFRAG(0, s);
          short8 as = AFRAG(1, s);
          MFMA(aR,  ap, rb1[k][0]);
          MFMA(aZ,  ap, rb1[k][1]);
          MFMA(aNI, ap, rb1[k][2]);
          MFMA(aR,  as, rb1[k][3]);
          MFMA(aZ,  as, rb1[k][4]);
          MFMA(aNH, as, rb1[k][5]);
          if (tt*16 + s + 4 < 64) L12_LOAD(k, tt*16 + s + 4, 1);
        }
      }
      #pragma unroll
      for (int i=0;i<4;++i){
        float hp = hm[1][tt][i];
        float r  = sigm(aR[i] + bir + bhr);
        float zg = sigm(aZ[i] + biz + bhz);
        float n  = tanh_(aNI[i] + bin + r*(aNH[i] + bhn));
        float hnew = (1.f - zg)*n + zg*hp;
        hm[1][tt][i] = (j < H_) ? hnew : 0.f;
      }
    }
    // prime layer2 ring
    #pragma unroll
    for (int p=0;p<4;++p) L12_LOAD(p, p, 3);
    __syncthreads();
    HWRITE(1);
    __syncthreads();

    // ---- mid-step pacing barrier (keeps the 16 WGs/XCD streaming the same L2 lines) ----
    if (tid == 0){
      __hip_atomic_fetch_add(bar, 1u, __ATOMIC_RELAXED, __HIP_MEMORY_SCOPE_AGENT);
      const unsigned tgt = (unsigned)NWG_ * (2u*t + 1u);
      while (__hip_atomic_load(bar, __ATOMIC_RELAXED, __HIP_MEMORY_SCOPE_AGENT) < tgt)
        __builtin_amdgcn_s_sleep(2);
    }
    __syncthreads();

    // ================= LAYER 2 =================
    #pragma unroll
    for (int tt=0; tt<4; ++tt){
      const int j = (wid + 8*tt)*16 + lcol;
      f32x4 aR=z4, aZ=z4, aNI=z4, aNH=z4;
      float bir=0.f,biz=0.f,bin=0.f,bhr=0.f,bhz=0.f,bhn=0.f;
      #pragma unroll
      for (int m=0;m<4;++m){
        if (m==2){
          bir = biasP[3*1536 + j]; biz = biasP[3*1536 + 512 + j]; bin = biasP[3*1536 + 1024 + j];
          bhr = biasP[4*1536 + j]; bhz = biasP[4*1536 + 512 + j]; bhn = biasP[4*1536 + 1024 + j];
        }
        #pragma unroll
        for (int k=0;k<4;++k){
          const int s = m*4+k;
          short8 ap = AFRAG(1, s);
          short8 as = AFRAG(2, s);
          MFMA(aR,  ap, rb1[k][0]);
          MFMA(aZ,  ap, rb1[k][1]);
          MFMA(aNI, ap, rb1[k][2]);
          MFMA(aR,  as, rb1[k][3]);
          MFMA(aZ,  as, rb1[k][4]);
          MFMA(aNH, as, rb1[k][5]);
          if (tt*16 + s + 4 < 64) L12_LOAD(k, tt*16 + s + 4, 3);
        }
      }
      #pragma unroll
      for (int i=0;i<4;++i){
        float hp = hm[2][tt][i];
        float r  = sigm(aR[i] + bir + bhr);
        float zg = sigm(aZ[i] + biz + bhz);
        float n  = tanh_(aNI[i] + bin + r*(aNH[i] + bhn));
        float hnew = (1.f - zg)*n + zg*hp;
        hm[2][tt][i] = (j < H_) ? hnew : 0.f;
      }
    }
    // prime logits ring + next step's layer0 ring
    if (wid < 4){
      #pragma unroll
      for (int p=0;p<4;++p) LL_LOAD(p, p);
    }
    #pragma unroll
    for (int p=0;p<4;++p) L0_LOAD(p, p);
    __syncthreads();
    HWRITE(2);
    __syncthreads();

    // ================= LOGITS (waves 0-3) =================
    if (wid < 4){
      f32x4 acc = z4;
      #pragma unroll
      for (int s=0;s<16;++s){
        short8 a = AFRAG(2, s);
        MFMA(acc, a, rbL[s&3]);
        if (s < 12) LL_LOAD(s&3, s+4);
      }
      const int j = wid*16 + lcol;
      float lb = linb[j];
      #pragma unroll
      for (int i=0;i<4;++i){
        const int m = lrow*4+i;
        out[(size_t)(b0+m)*(L_*V_) + (size_t)(t+1)*V_ + j] = acc[i] + lb;
      }
    }

    // ---- end-of-step pacing barrier ----
    if (tid == 0){
      __hip_atomic_fetch_add(bar, 1u, __ATOMIC_RELAXED, __HIP_MEMORY_SCOPE_AGENT);
      const unsigned tgt = (unsigned)NWG_ * (2u*t + 2u);
      while (__hip_atomic_load(bar, __ATOMIC_RELAXED, __HIP_MEMORY_SCOPE_AGENT) < tgt)
        __builtin_amdgcn_s_sleep(2);
    }
    __syncthreads();
  }
}

extern "C" void kernel_launch(void* const* d_in, const int* in_sizes, int n_in,
                              void* d_out, int out_size, void* d_ws, size_t ws_size,
                              hipStream_t stream)
{
  const float* z    = (const float*)d_in[0];
  const float* y    = (const float*)d_in[1];
  const int*   xin  = (const int*)d_in[2];
  const float* emb  = (const float*)d_in[3];
  const float* linw = (const float*)d_in[4];
  const float* linb = (const float*)d_in[5];
  const float* wih0 = (const float*)d_in[6];
  const float* whh0 = (const float*)d_in[7];
  const float* bih0 = (const float*)d_in[8];
  const float* bhh0 = (const float*)d_in[9];
  const float* wih1 = (const float*)d_in[10];
  const float* whh1 = (const float*)d_in[11];
  const float* bih1 = (const float*)d_in[12];
  const float* bhh1 = (const float*)d_in[13];
  const float* wih2 = (const float*)d_in[14];
  const float* whh2 = (const float*)d_in[15];
  const float* bih2 = (const float*)d_in[16];
  const float* bhh2 = (const float*)d_in[17];
  float* out = (float*)d_out;

  char* ws = (char*)d_ws;
  unsigned short* Wf    = (unsigned short*)(ws);                               // 7,864,320 B
  unsigned short* LinWf = (unsigned short*)(ws + 7864320);                     //    65,536 B
  float* EW    = (float*)(ws + 7864320 + 65536);                               //   393,216 B
  float* Cb    = (float*)(ws + 7864320 + 65536 + 393216);                      // 12,582,912 B
  float* BiasP = (float*)(ws + 7864320 + 65536 + 393216 + 12582912);           //    30,720 B
  unsigned* Bar = (unsigned*)(ws + 7864320 + 65536 + 393216 + 12582912 + 30720); // 64 B

  k_zero     <<<1, 64, 0, stream>>>(Bar);
  k_pack_w   <<<(15*32*16*512 + 255)/256, 256, 0, stream>>>(whh0, wih1, whh1, wih2, whh2, Wf);
  k_pack_linw<<<(4*16*512     + 255)/256, 256, 0, stream>>>(linw, LinWf);
  k_pack_bias<<<(5*1536       + 255)/256, 256, 0, stream>>>(bhh0, bih1, bhh1, bih2, bhh2, BiasP);
  k_ew       <<<(64*1536      + 255)/256, 256, 0, stream>>>(emb, wih0, EW);
  k_cb       <<<(B_*1536      + 255)/256, 256, 0, stream>>>(z, y, bih0, wih0, Cb);
  k_out0     <<<(B_*64        + 255)/256, 256, 0, stream>>>(out);
  k_gru      <<<NWG_, NTH_, 0, stream>>>(xin, Wf, LinWf, EW, Cb, BiasP, linb, out, Bar);
}

// Round 5
// 7259.323 us; speedup vs baseline: 9.3516x; 9.3516x over previous
//
#include <hip/hip_runtime.h>
#include <hip/hip_bf16.h>

#define B_   2048
#define L_   128
#define V_   64
#define H_   501
#define T_   127
#define NTH_ 512
#define TAU_END 130

typedef __attribute__((ext_vector_type(8))) short short8;
typedef __attribute__((ext_vector_type(4))) float f32x4;

#define MFMA(acc, a, b) acc = __builtin_amdgcn_mfma_f32_16x16x32_bf16((a), (b), (acc), 0, 0, 0)

__device__ __forceinline__ float sigm(float x){ return 1.f/(1.f + __expf(-x)); }
__device__ __forceinline__ float tanh_(float x){ float e = __expf(2.f*x); return 1.f - 2.f/(e + 1.f); }
__device__ __forceinline__ unsigned short f2bf(float x){
  unsigned u = __float_as_uint(x);
  u += 0x7fffu + ((u >> 16) & 1u);
  return (unsigned short)(u >> 16);
}

// ---------------- prologue kernels (verified R2-R4) ----------------

// Frag-linear weight pack: dst[mg][jt][s][lane][8], mg = mtx*3+gate (mtx: whh0,wih1,whh1,wih2,whh2)
__global__ void k_pack_w(const float* w0,const float* w1,const float* w2,const float* w3,const float* w4,
                         unsigned short* dst){
  int idx = blockIdx.x*256 + threadIdx.x;
  if (idx >= 15*32*16*512) return;
  int e  = idx & 7;
  int l  = (idx>>3) & 63;
  int s  = (idx>>9) & 15;
  int jt = (idx>>13) & 31;
  int mg = idx >> 18;
  int mtx = mg/3, g = mg%3;
  int j = jt*16 + (l & 15);
  int k = s*32 + ((l>>4)&3)*8 + e;
  const float* src = (mtx==0)?w0:(mtx==1)?w1:(mtx==2)?w2:(mtx==3)?w3:w4;
  float v = 0.f;
  if (j < H_ && k < H_) v = src[(size_t)(g*H_ + j)*H_ + k];
  dst[idx] = f2bf(v);
}

__global__ void k_pack_linw(const float* lw, unsigned short* dst){
  int idx = blockIdx.x*256 + threadIdx.x;
  if (idx >= 4*16*512) return;
  int e  = idx & 7;
  int l  = (idx>>3) & 63;
  int s  = (idx>>9) & 15;
  int jt = idx >> 13;
  int j = jt*16 + (l & 15);
  int k = s*32 + ((l>>4)&3)*8 + e;
  dst[idx] = f2bf((k < H_) ? lw[j*H_ + k] : 0.f);
}

__global__ void k_pack_bias(const float* b0,const float* b1,const float* b2,const float* b3,const float* b4,
                            float* dst){
  int idx = blockIdx.x*256 + threadIdx.x;
  if (idx >= 5*1536) return;
  int j = idx & 511; int g = (idx>>9)%3; int l = idx/1536;
  const float* s = (l==0)?b0:(l==1)?b1:(l==2)?b2:(l==3)?b3:b4;
  dst[idx] = (j < H_) ? s[g*H_ + j] : 0.f;
}

__global__ void k_ew(const float* emb, const float* wih0, float* EW){
  int idx = blockIdx.x*256 + threadIdx.x;
  if (idx >= 64*1536) return;
  int j = idx & 511; int g = (idx>>9)%3; int v = idx/1536;
  float s = 0.f;
  if (j < H_){
    const float* wr = wih0 + (size_t)(g*H_ + j)*257;
    const float* e  = emb + v*128;
    for (int k=0;k<128;++k) s += e[k]*wr[k];
  }
  EW[idx] = s;
}

__global__ void k_cb(const float* z, const float* y, const float* bih0, const float* wih0, float* Cb){
  int idx = blockIdx.x*256 + threadIdx.x;
  if (idx >= B_*1536) return;
  int j = idx & 511; int g = (idx>>9)%3; int b = idx/1536;
  float s = 0.f;
  if (j < H_){
    int row = g*H_ + j;
    const float* wr = wih0 + (size_t)row*257 + 128;
    const float* zr = z + b*128;
    s = bih0[row] + y[b]*wr[128];
    for (int k=0;k<128;++k) s += zr[k]*wr[k];
  }
  Cb[idx] = s;
}

__global__ void k_out0(float* out){
  int idx = blockIdx.x*256 + threadIdx.x;
  if (idx >= B_*64) return;
  int v = idx & 63, b = idx >> 6;
  out[(size_t)b*(L_*V_) + v] = (v==1) ? 1.f : 0.f;
}

__global__ void k_zero_all(f32x4* p, int n){
  int i = blockIdx.x*256 + threadIdx.x;
  if (i < n) p[i] = (f32x4){0.f,0.f,0.f,0.f};
}

// ---------------- LLC-coherent access helpers ----------------

// 4x16B device-coherent loads (bypass L1+L2 -> read at LLC), one waitcnt.
__device__ __forceinline__ void ld_sc4(const unsigned short* p, short8& a, short8& b, short8& c, short8& d){
  asm volatile("global_load_dwordx4 %0, %4, off sc0 sc1\n\t"
               "global_load_dwordx4 %1, %4, off offset:16 sc0 sc1\n\t"
               "global_load_dwordx4 %2, %4, off offset:32 sc0 sc1\n\t"
               "global_load_dwordx4 %3, %4, off offset:48 sc0 sc1\n\t"
               "s_waitcnt vmcnt(0)"
               : "=&v"(a), "=&v"(b), "=&v"(c), "=&v"(d) : "v"(p) : "memory");
}

// device-coherent 2B store (write-through past L2 so other XCDs see it at LLC)
__device__ __forceinline__ void st_sc_u16(unsigned short* p, unsigned v){
  asm volatile("global_store_short %0, %1, off sc0 sc1" :: "v"(p), "v"(v) : "memory");
}

__device__ __forceinline__ void spinwait(unsigned* f, unsigned tgt){
  while (__hip_atomic_fetch_add(f, 0u, __ATOMIC_RELAXED, __HIP_MEMORY_SCOPE_AGENT) < tgt)
    __builtin_amdgcn_s_sleep(4);
}

// stage 32 rows x 512 bf16 from a ring slot into a swizzled LDS A-buffer
__device__ __forceinline__ void stage32(char* lds, int bufoff,
                                        const unsigned short* ringslot, int b0, int tid){
  const int r = tid >> 4, seg = tid & 15;
  const unsigned short* src = ringslot + (((size_t)(b0 + r)) << 9) + seg*32;
  short8 v0, v1, v2, v3;
  ld_sc4(src, v0, v1, v2, v3);
  const int rt = r >> 4, rn = r & 15;
  const int base = bufoff + rt*16384 + rn*1024 + seg*64;
  const int sw = (rn & 7) << 4;
  *(short8*)(lds + ((base +  0) ^ sw)) = v0;
  *(short8*)(lds + ((base + 16) ^ sw)) = v1;
  *(short8*)(lds + ((base + 32) ^ sw)) = v2;
  *(short8*)(lds + ((base + 48) ^ sw)) = v3;
}

// ---------------- main pipelined kernel ----------------

#define AFR(OFF, RT, S) (*(const short8*)(lds + ((((OFF) + (RT)*16384 + (lcol<<10) + ((S)<<6) + (lrow<<4))) ^ ((lcol&7)<<4))))

#define L0B(SLOT, ITN) do{                                                       \
  const int itn_ = (ITN);                                                        \
  const unsigned short* p_ = wl + (size_t)(wid + 8*(itn_>>4))*8192 + (size_t)(itn_&15)*512; \
  rbA[SLOT][0] = *(const short8*)(p_);                                           \
  rbA[SLOT][1] = *(const short8*)(p_ + 262144);                                  \
  rbA[SLOT][2] = *(const short8*)(p_ + 524288); }while(0)

#define B6(SLOT, S) do{                                                          \
  const unsigned short* p_ = wb + (size_t)(S)*512;                               \
  rbB[SLOT][0] = *(const short8*)(p_);                                           \
  rbB[SLOT][1] = *(const short8*)(p_ + 262144);                                  \
  rbB[SLOT][2] = *(const short8*)(p_ + 524288);                                  \
  rbB[SLOT][3] = *(const short8*)(p_ + 786432);                                  \
  rbB[SLOT][4] = *(const short8*)(p_ + 1048576);                                 \
  rbB[SLOT][5] = *(const short8*)(p_ + 1310720); }while(0)

#define LLB(SLOT, S) do{ rbL[SLOT] = *(const short8*)(ll + (size_t)wid*8192 + (size_t)(S)*512); }while(0)

__global__ __launch_bounds__(NTH_, 2) void k_pipe(
    const int* __restrict__ xin, const unsigned short* __restrict__ Wf,
    const unsigned short* __restrict__ LinWf, const float* __restrict__ EW,
    const float* __restrict__ Cb, const float* __restrict__ biasP,
    const float* __restrict__ linb, float* __restrict__ out,
    unsigned* __restrict__ flags,
    unsigned short* __restrict__ ring0, unsigned short* __restrict__ ring1,
    unsigned short* __restrict__ ring2)
{
  __shared__ char lds[147456];   // 144 KB -> exactly 1 WG/CU; 256 WGs on 256 CUs

  const int tid  = threadIdx.x;
  const int wid  = tid >> 6;
  const int lane = tid & 63;
  const int lrow = lane >> 4;
  const int lcol = lane & 15;
  const int bid  = blockIdx.x;
  const int xcd  = bid & 7;          // default dispatch: round-robin bid -> XCD
  const int stage = xcd >> 1;        // stage s on XCD pair {2s, 2s+1}
  const int w    = ((bid >> 3) << 1) | (xcd & 1);   // 0..63 within stage
  const int b0   = w << 5;           // 32 batch rows per WG

  for (int i = tid; i < 147456/16; i += NTH_) ((f32x4*)lds)[i] = (f32x4){0,0,0,0};
  __syncthreads();

  const unsigned short* wl = Wf    + lane*8;
  const unsigned short* ll = LinWf + lane*8;
  const f32x4 z4 = {0.f,0.f,0.f,0.f};
  const int o1 = (stage+1)&3, o2 = (stage+2)&3, o3 = (stage+3)&3;

  #pragma unroll 1
  for (int tau = 0; tau < TAU_END; ++tau){
    // ---- wavefront flag waits: all other stages must have finished beat tau-1 ----
    if (tau >= 1){
      if (tid == 0)   spinwait(flags + o1*64 + w, (unsigned)tau);
      if (tid == 64)  spinwait(flags + o2*64 + w, (unsigned)tau);
      if (tid == 128) spinwait(flags + o3*64 + w, (unsigned)tau);
    }
    __syncthreads();

    // ---- stage A-operand inputs from rings (LLC-coherent) into swizzled LDS ----
    {
      const int s1 = (tau-1)&3, s2 = (tau-2)&3, s3 = (tau-3)&3;
      if (stage == 0){
        stage32(lds, 0,     ring0 + (size_t)s1*1048576, b0, tid);   // h0(tau-1)
        stage32(lds, 32768, ring2 + (size_t)s3*1048576, b0, tid);   // h2(tau-3) for logits
      } else if (stage == 1){
        stage32(lds, 0,     ring0 + (size_t)s1*1048576, b0, tid);   // h0(tau-1)
        stage32(lds, 32768, ring1 + (size_t)s2*1048576, b0, tid);   // h1(tau-2)
      } else if (stage == 2){
        stage32(lds, 0,     ring0 + (size_t)s1*1048576, b0, tid);
        stage32(lds, 32768, ring1 + (size_t)s2*1048576, b0, tid);
        stage32(lds, 65536, ring2 + (size_t)s3*1048576, b0, tid);   // h2(tau-3)
      } else {
        stage32(lds, 0,     ring1 + (size_t)s2*1048576, b0, tid);   // h1(tau-2)
        stage32(lds, 32768, ring2 + (size_t)s3*1048576, b0, tid);   // h2(tau-3)
      }
    }
    __syncthreads();

    if (stage == 0){
      // =============== L0: h0(tau) = GRU(gi0(tok,cond), h0(tau-1)) ===============
      if (tau <= T_-1){
        const int t = tau;
        int tk[8];
        #pragma unroll
        for (int rt=0; rt<2; ++rt)
          #pragma unroll
          for (int i=0;i<4;++i){
            int m = rt*16 + lrow*4 + i;
            tk[rt*4+i] = (t==0) ? 1 : xin[(b0+m)*L_ + t];
          }
        unsigned short* rdst = ring0 + (size_t)(t&3)*1048576;
        float* M = (float*)(lds + 65536);           // fp32 master h0 [32][512]
        short8 rbA[4][3];
        L0B(0,0); L0B(1,1); L0B(2,2); L0B(3,3);
        #pragma unroll 1
        for (int q = 0; q < 4; ++q){
          const int jt = wid + 8*q;
          const int j  = jt*16 + lcol;
          f32x4 aR[2]={z4,z4}, aZ[2]={z4,z4}, aN[2]={z4,z4};
          float gr[2][4], gz[2][4], gn[2][4];
          float br=0.f, bz=0.f, bn=0.f;
          #pragma unroll
          for (int s=0;s<16;++s){
            if (s==2){
              br = biasP[j]; bz = biasP[512+j]; bn = biasP[1024+j];
              #pragma unroll
              for (int rt=0;rt<2;++rt)
                #pragma unroll
                for (int i=0;i<4;++i){
                  int m = rt*16+lrow*4+i;
                  const float* ewp = EW + tk[rt*4+i]*1536;
                  const float* cbp = Cb + (size_t)(b0+m)*1536;
                  gr[rt][i] = ewp[j]      + __builtin_nontemporal_load(cbp + j);
                  gz[rt][i] = ewp[512+j]  + __builtin_nontemporal_load(cbp + 512 + j);
                  gn[rt][i] = ewp[1024+j] + __builtin_nontemporal_load(cbp + 1024 + j);
                }
            }
            short8 a0 = AFR(0, 0, s), a1 = AFR(0, 1, s);
            MFMA(aR[0], a0, rbA[s&3][0]); MFMA(aZ[0], a0, rbA[s&3][1]); MFMA(aN[0], a0, rbA[s&3][2]);
            MFMA(aR[1], a1, rbA[s&3][0]); MFMA(aZ[1], a1, rbA[s&3][1]); MFMA(aN[1], a1, rbA[s&3][2]);
            int itn = q*16 + s + 4;
            if (itn < 64) L0B((s+4)&3, itn);
          }
          #pragma unroll
          for (int rt=0;rt<2;++rt)
            #pragma unroll
            for (int i=0;i<4;++i){
              int m = rt*16+lrow*4+i;
              float hp = M[m*512 + j];
              float r  = sigm(gr[rt][i] + aR[rt][i] + br);
              float zg = sigm(gz[rt][i] + aZ[rt][i] + bz);
              float n  = tanh_(gn[rt][i] + r*(aN[rt][i] + bn));
              float hnew = (1.f - zg)*n + zg*hp;
              hnew = (j < H_) ? hnew : 0.f;
              M[m*512 + j] = hnew;
              st_sc_u16(rdst + (((size_t)(b0+m))<<9) + j, (unsigned)f2bf(hnew));
            }
        }
      }
      // =============== logits for beat tau-3 (waves 0-3) ===============
      if (tau >= 3 && wid < 4){
        const int beta = tau - 3;
        const int j = wid*16 + lcol;
        short8 rbL[4];
        LLB(0,0); LLB(1,1); LLB(2,2); LLB(3,3);
        f32x4 acc[2] = {z4, z4};
        #pragma unroll
        for (int s=0;s<16;++s){
          short8 a0 = AFR(32768, 0, s), a1 = AFR(32768, 1, s);
          MFMA(acc[0], a0, rbL[s&3]);
          MFMA(acc[1], a1, rbL[s&3]);
          if (s < 12) LLB(s&3, s+4);
        }
        float lb = linb[j];
        #pragma unroll
        for (int rt=0;rt<2;++rt)
          #pragma unroll
          for (int i=0;i<4;++i){
            int m = rt*16+lrow*4+i;
            out[(size_t)(b0+m)*(L_*V_) + (size_t)(beta+1)*V_ + j] = acc[rt][i] + lb;
          }
      }
    } else {
      // =============== stages 1-3: unified (layer, jt) item list ===============
      const int NI = (stage==3) ? 22 : 21;
      #pragma unroll 1
      for (int itm = wid; itm < NI; itm += 8){
        int lyr, jt;
        if (stage == 1){ lyr = 1; jt = itm; }
        else if (stage == 2){ if (itm < 11){ lyr = 1; jt = 21 + itm; } else { lyr = 2; jt = itm - 11; } }
        else { lyr = 2; jt = 10 + itm; }
        const bool act = (lyr==1) ? (tau>=1 && tau<=T_) : (tau>=2 && tau<=T_+1);
        if (!act) continue;

        const int mI = (lyr==1) ? 1 : 3;
        const unsigned short* wb = wl + (size_t)mI*786432 + (size_t)jt*8192;
        const int bI = mI*1536, bH = (mI+1)*1536;
        int apOff, asOff, mOff, mW, jt0;
        unsigned short* rdst;
        if (lyr == 1){
          apOff = 0; asOff = 32768;
          rdst = ring1 + (size_t)((tau-1)&3)*1048576;
          if (stage == 1){ mOff = 65536; mW = 336; jt0 = 0; }
          else           { mOff = 98304; mW = 176; jt0 = 21; }
        } else {
          if (stage == 2){ apOff = 32768; asOff = 65536; mOff = 120832; mW = 160; jt0 = 0; }
          else           { apOff = 0;     asOff = 32768; mOff = 65536;  mW = 352; jt0 = 10; }
          rdst = ring2 + (size_t)((tau-2)&3)*1048576;
        }
        const int j    = jt*16 + lcol;
        const int jloc = (jt - jt0)*16 + lcol;

        short8 rbB[4][6];
        B6(0,0); B6(1,1); B6(2,2); B6(3,3);
        f32x4 aR[2]={z4,z4}, aZ[2]={z4,z4}, aNI_[2]={z4,z4}, aNH[2]={z4,z4};
        #pragma unroll
        for (int s=0;s<16;++s){
          short8 p0 = AFR(apOff,0,s), p1 = AFR(apOff,1,s);
          short8 c0 = AFR(asOff,0,s), c1 = AFR(asOff,1,s);
          MFMA(aR[0],  p0, rbB[s&3][0]); MFMA(aZ[0], p0, rbB[s&3][1]); MFMA(aNI_[0], p0, rbB[s&3][2]);
          MFMA(aR[0],  c0, rbB[s&3][3]); MFMA(aZ[0], c0, rbB[s&3][4]); MFMA(aNH[0],  c0, rbB[s&3][5]);
          MFMA(aR[1],  p1, rbB[s&3][0]); MFMA(aZ[1], p1, rbB[s&3][1]); MFMA(aNI_[1], p1, rbB[s&3][2]);
          MFMA(aR[1],  c1, rbB[s&3][3]); MFMA(aZ[1], c1, rbB[s&3][4]); MFMA(aNH[1],  c1, rbB[s&3][5]);
          if (s < 12) B6(s&3, s+4);
        }
        float bir = biasP[bI + j], biz = biasP[bI + 512 + j], bin = biasP[bI + 1024 + j];
        float bhr = biasP[bH + j], bhz = biasP[bH + 512 + j], bhn = biasP[bH + 1024 + j];
        float* M = (float*)(lds + mOff);
        #pragma unroll
        for (int rt=0;rt<2;++rt)
          #pragma unroll
          for (int i=0;i<4;++i){
            int m = rt*16 + lrow*4 + i;
            float hp = M[m*mW + jloc];
            float r  = sigm(aR[rt][i] + bir + bhr);
            float zg = sigm(aZ[rt][i] + biz + bhz);
            float n  = tanh_(aNI_[rt][i] + bin + r*(aNH[rt][i] + bhn));
            float hnew = (1.f - zg)*n + zg*hp;
            hnew = (j < H_) ? hnew : 0.f;
            M[m*mW + jloc] = hnew;
            st_sc_u16(rdst + (((size_t)(b0+m))<<9) + j, (unsigned)f2bf(hnew));
          }
      }
    }

    // ---- publish: all ring stores drained, then release flag = tau+1 ----
    asm volatile("s_waitcnt vmcnt(0)" ::: "memory");
    __syncthreads();
    if (tid == 0)
      __hip_atomic_store(flags + stage*64 + w, (unsigned)(tau+1),
                         __ATOMIC_RELEASE, __HIP_MEMORY_SCOPE_AGENT);
  }
}

// ---------------- launch ----------------

#define WS_WF     0
#define WS_LINW   7864320
#define WS_EW     7929856
#define WS_CB     8323072
#define WS_BIAS   20905984
#define WS_FLAGS  20936704
#define WS_RINGS  20940800
#define RING_ELE  (4*2048*512)        // ushorts per ring (depth 4)

extern "C" void kernel_launch(void* const* d_in, const int* in_sizes, int n_in,
                              void* d_out, int out_size, void* d_ws, size_t ws_size,
                              hipStream_t stream)
{
  const float* z    = (const float*)d_in[0];
  const float* y    = (const float*)d_in[1];
  const int*   xin  = (const int*)d_in[2];
  const float* emb  = (const float*)d_in[3];
  const float* linw = (const float*)d_in[4];
  const float* linb = (const float*)d_in[5];
  const float* wih0 = (const float*)d_in[6];
  const float* whh0 = (const float*)d_in[7];
  const float* bih0 = (const float*)d_in[8];
  const float* bhh0 = (const float*)d_in[9];
  const float* wih1 = (const float*)d_in[10];
  const float* whh1 = (const float*)d_in[11];
  const float* bih1 = (const float*)d_in[12];
  const float* bhh1 = (const float*)d_in[13];
  const float* wih2 = (const float*)d_in[14];
  const float* whh2 = (const float*)d_in[15];
  const float* bih2 = (const float*)d_in[16];
  const float* bhh2 = (const float*)d_in[17];
  float* out = (float*)d_out;

  char* ws = (char*)d_ws;
  unsigned short* Wf    = (unsigned short*)(ws + WS_WF);
  unsigned short* LinWf = (unsigned short*)(ws + WS_LINW);
  float* EW    = (float*)(ws + WS_EW);
  float* Cb    = (float*)(ws + WS_CB);
  float* BiasP = (float*)(ws + WS_BIAS);
  unsigned* Flags = (unsigned*)(ws + WS_FLAGS);
  unsigned short* Ring0 = (unsigned short*)(ws + WS_RINGS);
  unsigned short* Ring1 = Ring0 + RING_ELE;
  unsigned short* Ring2 = Ring1 + RING_ELE;

  // zero flags + rings (4096 + 3*8388608 bytes = 25169920 -> 1573120 x 16B)
  k_zero_all <<<(1573120 + 255)/256, 256, 0, stream>>>((f32x4*)(ws + WS_FLAGS), 1573120);
  k_pack_w   <<<(15*32*16*512 + 255)/256, 256, 0, stream>>>(whh0, wih1, whh1, wih2, whh2, Wf);
  k_pack_linw<<<(4*16*512     + 255)/256, 256, 0, stream>>>(linw, LinWf);
  k_pack_bias<<<(5*1536       + 255)/256, 256, 0, stream>>>(bhh0, bih1, bhh1, bih2, bhh2, BiasP);
  k_ew       <<<(64*1536      + 255)/256, 256, 0, stream>>>(emb, wih0, EW);
  k_cb       <<<(B_*1536      + 255)/256, 256, 0, stream>>>(z, y, bih0, wih0, Cb);
  k_out0     <<<(B_*64        + 255)/256, 256, 0, stream>>>(out);
  k_pipe     <<<256, NTH_, 0, stream>>>(xin, Wf, LinWf, EW, Cb, BiasP, linb, out,
                                        Flags, Ring0, Ring1, Ring2);
}